// Round 19
// baseline (492.531 us; speedup 1.0000x reference)
//
#include <hip/hip_runtime.h>

#define CH 64

typedef short s16x8 __attribute__((ext_vector_type(8)));
typedef float f32x4 __attribute__((ext_vector_type(4)));

static __device__ __forceinline__ ushort f2bf(float f) {
    union { float f; uint u; } v; v.f = f;
    const uint r = (v.u + 0x7FFFu + ((v.u >> 16) & 1u)) >> 16;
    return (ushort)r;
}
static __device__ __forceinline__ float bf2f(ushort u) {
    union { uint u; float f; } v; v.u = ((uint)u) << 16; return v.f;
}

// =====================================================================
// Prepack encoder weights (5,64,64,4) [o][i][tau] -> [L][i][o][tau]
// =====================================================================
__global__ __launch_bounds__(256) void k_prepack_enc(
    const float* __restrict__ enc_w, float* __restrict__ encW)
{
    const int idx = blockIdx.x * 256 + threadIdx.x;   // 81920
    const int tau = idx & 3;
    const int o = (idx >> 2) & 63;
    const int i = (idx >> 8) & 63;
    const int L = idx >> 14;
    encW[idx] = enc_w[(((size_t)L * 64 + o) * 64 + i) * 4 + tau];
}

// acc = fmaf chain over 4 taps
#define ACC4(A, W, L, H) \
    A = fmaf((W).w, (H).y, fmaf((W).z, (H).x, fmaf((W).y, (L).y, fmaf((W).x, (L).x, (A)))))

// =====================================================================
// ENCODER (fp32): T-pos tile, 256 threads, 16 channels staged/phase.
// ii-loop unrolled x2 so next-iter weight loads hide under current FMAs.
// =====================================================================
template<int T>
__device__ __forceinline__ void conv_accum_t(
    const float (*inT)[2 * T + 8], const float* __restrict__ wpk, int ibase,
    float acc[4][T / 16], int og, int pg)
{
    const float* wI = wpk + og * 16 + (size_t)ibase * 256;
#pragma unroll 2
    for (int ii = 0; ii < 16; ++ii) {
        const float* wp = wI + ii * 256;
        const float4 w0 = *(const float4*)(wp + 0);
        const float4 w1 = *(const float4*)(wp + 4);
        const float4 w2 = *(const float4*)(wp + 8);
        const float4 w3 = *(const float4*)(wp + 12);
        const float* row = inT[ii];
#pragma unroll
        for (int j = 0; j < T / 32; ++j) {
            const int base = 4 * pg + 64 * j;
            const float2 xa = *(const float2*)(row + base);
            const float2 xb = *(const float2*)(row + base + 2);
            const float2 xc = *(const float2*)(row + base + 4);
            ACC4(acc[0][2*j],   w0, xa, xb);
            ACC4(acc[1][2*j],   w1, xa, xb);
            ACC4(acc[2][2*j],   w2, xa, xb);
            ACC4(acc[3][2*j],   w3, xa, xb);
            ACC4(acc[0][2*j+1], w0, xb, xc);
            ACC4(acc[1][2*j+1], w1, xb, xc);
            ACC4(acc[2][2*j+1], w2, xb, xc);
            ACC4(acc[3][2*j+1], w3, xb, xc);
        }
    }
}

template<int T>
__device__ __forceinline__ void conv_epilogue_t(
    float acc[4][T / 16], float* __restrict__ out,
    int b, int m0, int Lout, int transpose, int og, int pg)
{
    if (!transpose) {
#pragma unroll
        for (int oo = 0; oo < 4; ++oo) {
            float* ob = out + ((size_t)b * CH + og * 4 + oo) * Lout + m0 + 2 * pg;
#pragma unroll
            for (int j = 0; j < T / 32; ++j) {
                float2 v;
                v.x = fmaxf(acc[oo][2*j], 0.f);
                v.y = fmaxf(acc[oo][2*j+1], 0.f);
                *(float2*)(ob + 32 * j) = v;
            }
        }
    } else {
#pragma unroll
        for (int j = 0; j < T / 32; ++j)
#pragma unroll
            for (int h = 0; h < 2; ++h) {
                const int ml = 2 * pg + 32 * j + h;
                float* ob = out + ((size_t)b * Lout + m0 + ml) * CH + og * 4;
                float4 v;
                v.x = fmaxf(acc[0][2*j+h], 0.f);
                v.y = fmaxf(acc[1][2*j+h], 0.f);
                v.z = fmaxf(acc[2][2*j+h], 0.f);
                v.w = fmaxf(acc[3][2*j+h], 0.f);
                *(float4*)ob = v;
            }
    }
}

template<int T>
__global__ __launch_bounds__(256) void k_enc_conv_t(
    const float* __restrict__ in, const float* __restrict__ wpk,
    const float* __restrict__ bias, float* __restrict__ out,
    int Lin, int Lout, int transpose)
{
    __shared__ float inT[16][2 * T + 8];
    const int m0 = blockIdx.x * T;
    const int b = blockIdx.y;
    const int tid = threadIdx.x;
    const int og = tid >> 4, pg = tid & 15;
    const float* inb = in + (size_t)b * CH * Lin;
    float acc[4][T / 16];
#pragma unroll
    for (int oo = 0; oo < 4; ++oo) {
        const float bv = bias[og * 4 + oo];
#pragma unroll
        for (int j = 0; j < T / 16; ++j) acc[oo][j] = bv;
    }
    for (int q = 0; q < 4; ++q) {
        {   // stage rows q*16..q*16+15
            const int r = tid >> 4;
            const int i = q * 16 + r;
            const int seg = tid & 15;
            const float* src = inb + (size_t)i * Lin + 2 * m0 + 4 * seg;
            float* dst = inT[r] + 1 + 4 * seg;
#pragma unroll
            for (int t = 0; t < T / 32; ++t) {
                const float4 v = *(const float4*)(src + 64 * t);
                float* d = dst + 64 * t;
                d[0] = v.x;
                *(float2*)(d + 1) = make_float2(v.y, v.z);
                d[3] = v.w;
            }
            if (tid < 32) {                    // edges pl=0 and pl=2T+1
                const int rr = tid & 15, side = tid >> 4;
                const int pl = side ? (2 * T + 1) : 0;
                const int p = 2 * m0 - 1 + pl;
                inT[rr][pl] = (p >= 0 && p < Lin) ? inb[(size_t)(q * 16 + rr) * Lin + p] : 0.f;
            }
        }
        __syncthreads();
        conv_accum_t<T>(inT, wpk, q * 16, acc, og, pg);
        __syncthreads();
    }
    conv_epilogue_t<T>(acc, out, b, m0, Lout, transpose, og, pg);
}

// fused conv0 (1->64) + conv1 (64->64), T=128
__global__ __launch_bounds__(256) void k_enc01(
    const float* __restrict__ x, const float* __restrict__ w0,
    const float* __restrict__ b0, const float* __restrict__ wpk0,
    const float* __restrict__ b1, float* __restrict__ out)
{
    __shared__ float xl[520];
    __shared__ float e0s[16][264];
    const int m0 = blockIdx.x * 128;
    const int b = blockIdx.y;
    const int tid = threadIdx.x;
    const int og = tid >> 4, pg = tid & 15;
    const bool interior = (blockIdx.x != 0) && (blockIdx.x != gridDim.x - 1);
    const float* xb = x + (size_t)b * 65536;
    const int x0i = 4 * m0 - 3;
    if (interior) {
        for (int xi = tid; xi < 518; xi += 256) xl[xi] = xb[x0i + xi];
    } else {
        for (int xi = tid; xi < 518; xi += 256) {
            const int q = x0i + xi;
            xl[xi] = (q >= 0 && q < 65536) ? xb[q] : 0.f;
        }
    }
    float acc[4][8];
#pragma unroll
    for (int oo = 0; oo < 4; ++oo) {
        const float bv = b1[og * 4 + oo];
#pragma unroll
        for (int j = 0; j < 8; ++j) acc[oo][j] = bv;
    }
    const int r = tid >> 4;            // e0 row worker 0..15
    const int oct = tid & 15;          // 16 slots x 17 values
    const int pbase = 2 * m0 - 1;      // e0-pos of pl=0; e0 length = 32768
    __syncthreads();
    for (int q = 0; q < 4; ++q) {
        {
            const int i = q * 16 + r;
            const float4 wv = *(const float4*)(w0 + i * 4);
            const float bv = b0[i];
            if (interior) {
                for (int t = 0; t < 17; ++t) {
                    const int pl = oct * 17 + t;
                    if (pl < 258) {
                        const float* xp = xl + 2 * pl;
                        const float v = fmaf(wv.w, xp[3], fmaf(wv.z, xp[2],
                                        fmaf(wv.y, xp[1], fmaf(wv.x, xp[0], bv))));
                        e0s[r][pl] = fmaxf(v, 0.f);
                    }
                }
            } else {
                for (int t = 0; t < 17; ++t) {
                    const int pl = oct * 17 + t;
                    if (pl < 258) {
                        const int pe = pbase + pl;
                        const float* xp = xl + 2 * pl;
                        const float v = fmaf(wv.w, xp[3], fmaf(wv.z, xp[2],
                                        fmaf(wv.y, xp[1], fmaf(wv.x, xp[0], bv))));
                        e0s[r][pl] = (pe >= 0 && pe < 32768) ? fmaxf(v, 0.f) : 0.f;
                    }
                }
            }
        }
        __syncthreads();
        conv_accum_t<128>(e0s, wpk0, q * 16, acc, og, pg);
        __syncthreads();
    }
    conv_epilogue_t<128>(acc, out, b, m0, 16384, 0, og, pg);
}

// =====================================================================
// VQ — unchanged (g written as padded bf16 [tok][d])
// =====================================================================
__global__ __launch_bounds__(512) void k_vq(
    const float* __restrict__ z, const float* __restrict__ cb,
    float* __restrict__ idsf, ushort* __restrict__ g)
{
    __shared__ float c2s[1024];
    __shared__ float rval[8][64];
    __shared__ int   ridx[8][64];
    __shared__ int   widx[64];
    const int t0 = blockIdx.x * 64;
    const int tid = threadIdx.x;
    const int lane = tid & 63;
    const int wv = __builtin_amdgcn_readfirstlane(tid >> 6);

    for (int c = tid; c < 1024; c += 512) {
        const float* cp = cb + (size_t)c * 64;
        float s0 = 0.f, s1 = 0.f, s2 = 0.f, s3 = 0.f;
#pragma unroll
        for (int d = 0; d < 64; d += 4) {
            const float4 v = *(const float4*)(cp + d);
            s0 += v.x * v.x; s1 += v.y * v.y; s2 += v.z * v.z; s3 += v.w * v.w;
        }
        c2s[c] = (s0 + s1) + (s2 + s3);
    }
    float pz[64];
    {
        const float* zp = z + (size_t)(t0 + lane) * 64;
#pragma unroll
        for (int d = 0; d < 64; d += 4) {
            const float4 v = *(const float4*)(zp + d);
            pz[d] = -2.f * v.x; pz[d + 1] = -2.f * v.y;
            pz[d + 2] = -2.f * v.z; pz[d + 3] = -2.f * v.w;
        }
    }
    __syncthreads();
    float best = 3.0e38f; int bidx = 0;
    const int cbase = wv * 128;
    for (int cc = 0; cc < 128; ++cc) {
        const int code = cbase + cc;
        const float* cp = cb + (size_t)code * 64;   // uniform -> s_load
        float a0 = 0.f, a1 = 0.f, a2 = 0.f, a3 = 0.f;
#pragma unroll
        for (int d = 0; d < 64; d += 4) {
            a0 += cp[d] * pz[d];
            a1 += cp[d + 1] * pz[d + 1];
            a2 += cp[d + 2] * pz[d + 2];
            a3 += cp[d + 3] * pz[d + 3];
        }
        const float dist = c2s[code] + ((a0 + a1) + (a2 + a3));
        if (dist < best) { best = dist; bidx = code; }
    }
    rval[wv][lane] = best; ridx[wv][lane] = bidx;
    __syncthreads();
    if (tid < 64) {
        float bv = rval[0][tid]; int bi = ridx[0][tid];
#pragma unroll
        for (int k2 = 1; k2 < 8; ++k2) {
            const float v = rval[k2][tid];
            if (v < bv) { bv = v; bi = ridx[k2][tid]; }
        }
        widx[tid] = bi;
        idsf[t0 + tid] = (float)bi;
    }
    __syncthreads();
    const int bb = t0 >> 10;
    const int mb = t0 & 1023;
    ushort* gb = g + ((size_t)bb * 1026 + 1 + mb) * 64;
    for (int e = tid; e < 4096; e += 512) {
        const int d = e & 63;
        const int tok = e >> 6;
        gb[(size_t)tok * 64 + d] = f2bf(cb[(size_t)widx[tok] * 64 + d]);
    }
    if (mb == 0 && tid < 16) {
        ushort4 zz = {0, 0, 0, 0};
        *(ushort4*)(g + ((size_t)bb * 1026) * 64 + tid * 4) = zz;
    }
    if (mb == 960 && tid < 16) {
        ushort4 zz = {0, 0, 0, 0};
        *(ushort4*)(g + ((size_t)bb * 1026 + 1025) * 64 + tid * 4) = zz;
    }
}

// =====================================================================
// DECODER: padded bf16 [n][ch] inter-layer format. k_dec2t<NCG,PAD>
// 1-wave blocks; NCG u-col groups share the wave's A-fragment loads.
// =====================================================================
__global__ __launch_bounds__(256) void k_prepack(
    const float* __restrict__ dec_w, ushort* __restrict__ Afrag)
{
    const int idx = blockIdx.x * 256 + threadIdx.x;   // 81920
    const int j    = idx & 7;
    const int lane = (idx >> 3) & 63;
    const int kt   = (idx >> 9) & 1;
    const int m    = (idx >> 10) & 3;
    const int tap  = (idx >> 12) & 3;
    const int L    = idx >> 14;
    const int o = m * 16 + (lane & 15);
    const int i = kt * 32 + ((lane >> 4) << 3) + j;
    Afrag[idx] = f2bf(dec_w[(((size_t)L * 64 + i) * 64 + o) * 4 + tap]);
}

template<int NCG, bool PAD>
__global__ __launch_bounds__(64) void k_dec2t(
    const ushort* __restrict__ Xt, const ushort* __restrict__ AfragL,
    const float* __restrict__ bias, ushort* __restrict__ Yt, int Lin)
{
    const int u0 = blockIdx.x * (16 * NCG);
    const int b  = blockIdx.y;
    const int tid = threadIdx.x;
    const int Lout = Lin * 2;
    const ushort* Xb = Xt + ((size_t)b * (Lin + 2) + 1) * 64;
    ushort* Yb = PAD ? Yt + ((size_t)b * (Lout + 2) + 1) * 64
                     : Yt + (size_t)b * Lout * 64;

    const int lane = tid & 63;
    const int col = lane & 15, kg = lane >> 4;
    s16x8 Bm1[NCG][2], B0[NCG][2], Bp1[NCG][2];
#pragma unroll
    for (int g = 0; g < NCG; ++g) {
        const ushort* basep = Xb + (size_t)(u0 + col + 16 * g) * 64 + kg * 8;
#pragma unroll
        for (int kt = 0; kt < 2; ++kt) {
            Bm1[g][kt] = *(const s16x8*)(basep - 64 + kt * 32);
            B0[g][kt]  = *(const s16x8*)(basep + kt * 32);
            Bp1[g][kt] = *(const s16x8*)(basep + 64 + kt * 32);
        }
    }
    const s16x8* Af = (const s16x8*)AfragL;
#pragma unroll
    for (int m = 0; m < 4; ++m) {
        s16x8 a1[2], a3[2], a2[2], a0[2];
#pragma unroll
        for (int kt = 0; kt < 2; ++kt) {
            a1[kt] = Af[((1 * 4 + m) * 2 + kt) * 64 + lane];
            a3[kt] = Af[((3 * 4 + m) * 2 + kt) * 64 + lane];
            a2[kt] = Af[((2 * 4 + m) * 2 + kt) * 64 + lane];
            a0[kt] = Af[((0 * 4 + m) * 2 + kt) * 64 + lane];
        }
        const float4 bm4 = *(const float4*)(bias + m * 16 + kg * 4);
        const float bb[4] = {bm4.x, bm4.y, bm4.z, bm4.w};
#pragma unroll
        for (int g = 0; g < NCG; ++g) {
            f32x4 aE = {0.f, 0.f, 0.f, 0.f};
            f32x4 aO = {0.f, 0.f, 0.f, 0.f};
#pragma unroll
            for (int kt = 0; kt < 2; ++kt) {
                aE = __builtin_amdgcn_mfma_f32_16x16x32_bf16(a1[kt], B0[g][kt],  aE, 0, 0, 0);
                aE = __builtin_amdgcn_mfma_f32_16x16x32_bf16(a3[kt], Bm1[g][kt], aE, 0, 0, 0);
                aO = __builtin_amdgcn_mfma_f32_16x16x32_bf16(a2[kt], B0[g][kt],  aO, 0, 0, 0);
                aO = __builtin_amdgcn_mfma_f32_16x16x32_bf16(a0[kt], Bp1[g][kt], aO, 0, 0, 0);
            }
            const size_t n2 = 2 * (size_t)(u0 + col + 16 * g);
            ushort4 pe, po;
            pe.x = f2bf(fmaxf(aE[0] + bb[0], 0.f));
            pe.y = f2bf(fmaxf(aE[1] + bb[1], 0.f));
            pe.z = f2bf(fmaxf(aE[2] + bb[2], 0.f));
            pe.w = f2bf(fmaxf(aE[3] + bb[3], 0.f));
            po.x = f2bf(fmaxf(aO[0] + bb[0], 0.f));
            po.y = f2bf(fmaxf(aO[1] + bb[1], 0.f));
            po.z = f2bf(fmaxf(aO[2] + bb[2], 0.f));
            po.w = f2bf(fmaxf(aO[3] + bb[3], 0.f));
            *(ushort4*)(Yb + n2 * 64 + m * 16 + kg * 4) = pe;
            *(ushort4*)(Yb + (n2 + 1) * 64 + m * 16 + kg * 4) = po;
        }
    }
    if (PAD) {
        if (blockIdx.x == 0 && tid < 16) {
            ushort4 zz = {0, 0, 0, 0};
            *(ushort4*)(Yt + ((size_t)b * (Lout + 2)) * 64 + tid * 4) = zz;
        }
        if (u0 + 16 * NCG >= Lin && tid < 16) {
            ushort4 zz = {0, 0, 0, 0};
            *(ushort4*)(Yb + (size_t)Lout * 64 + tid * 4) = zz;
        }
    }
}

// last convT (64->1, no relu): y[2v] / y[2v+1] from d4t rows v-1, v, v+1.
__global__ __launch_bounds__(256) void k_y(
    const ushort* __restrict__ d4t, const float* __restrict__ wl,
    const float* __restrict__ blp, float* __restrict__ y, int bbase)
{
    const int v = blockIdx.x * 256 + threadIdx.x;
    const int b = blockIdx.y;
    const ushort* r0 = d4t + ((size_t)b * 32768 + v) * 64;
    const bool hm = v > 0, hp = v < 32767;
    const ushort* rm = hm ? r0 - 64 : r0;
    const ushort* rp = hp ? r0 + 64 : r0;
    const s16x8 zv = {0, 0, 0, 0, 0, 0, 0, 0};
    float y0a = 0.f, y0b = 0.f, y1a = 0.f, y1b = 0.f;
#pragma unroll
    for (int c = 0; c < 8; ++c) {
        const s16x8 a0 = *(const s16x8*)(r0 + 8 * c);
        s16x8 am = *(const s16x8*)(rm + 8 * c);
        s16x8 ap = *(const s16x8*)(rp + 8 * c);
        if (!hm) am = zv;
        if (!hp) ap = zv;
#pragma unroll
        for (int e = 0; e < 8; e += 2) {
            const float4 wA = *(const float4*)(wl + (8 * c + e) * 4);
            const float4 wB = *(const float4*)(wl + (8 * c + e + 1) * 4);
            y0a = fmaf(wA.y, bf2f((ushort)a0[e]),     fmaf(wA.w, bf2f((ushort)am[e]),     y0a));
            y1a = fmaf(wA.z, bf2f((ushort)a0[e]),     fmaf(wA.x, bf2f((ushort)ap[e]),     y1a));
            y0b = fmaf(wB.y, bf2f((ushort)a0[e + 1]), fmaf(wB.w, bf2f((ushort)am[e + 1]), y0b));
            y1b = fmaf(wB.z, bf2f((ushort)a0[e + 1]), fmaf(wB.x, bf2f((ushort)ap[e + 1]), y1b));
        }
    }
    float2 out;
    out.x = blp[0] + (y0a + y0b);
    out.y = blp[0] + (y1a + y1b);
    *(float2*)(y + (size_t)(bbase + b) * 65536 + 2 * v) = out;
}

extern "C" void kernel_launch(void* const* d_in, const int* in_sizes, int n_in,
                              void* d_out, int out_size, void* d_ws, size_t ws_size,
                              hipStream_t stream) {
    const float* x      = (const float*)d_in[0];
    const float* enc_w0 = (const float*)d_in[1];
    const float* enc_w  = (const float*)d_in[2];   // (5,64,64,4)
    const float* enc_b  = (const float*)d_in[3];   // (6,64)
    const float* cb     = (const float*)d_in[4];   // (1024,64)
    const float* dec_w  = (const float*)d_in[5];   // (5,64,64,4) [in][out][k]
    const float* dec_wl = (const float*)d_in[6];   // (64,1,4)
    const float* dec_b  = (const float*)d_in[7];   // (5,64)
    const float* dec_bl = (const float*)d_in[8];   // (1,)
    float* y    = (float*)d_out;                   // (16,1,65536)
    float* z_e  = y + 1048576;                     // (16384,64)
    float* idsf = y + 2097152;                     // (16384,)

    // workspace overlay: A = 16.7M floats (67MB), Bf = 8.4M floats (33.6MB)
    float* A  = (float*)d_ws;
    float* Bf = A + 16777216;

    float*  encW  = y + 14 * 65536;
    ushort* Afrag = (ushort*)(encW + 81920);

    k_prepack_enc<<<dim3(320), 256, 0, stream>>>(enc_w, encW);
    k_prepack<<<dim3(320), 256, 0, stream>>>(dec_w, Afrag);

    // encoder (fp32); tail layers tiled for 8 blocks/CU residency
    k_enc01<<<dim3(128, 16), 256, 0, stream>>>(x, enc_w0, enc_b, encW, enc_b + 64, A);
    k_enc_conv_t<64><<<dim3(128, 16), 256, 0, stream>>>(A,  encW + 1 * 16384, enc_b + 2 * 64, Bf, 16384, 8192, 0);
    k_enc_conv_t<32><<<dim3(128, 16), 256, 0, stream>>>(Bf, encW + 2 * 16384, enc_b + 3 * 64, A,  8192,  4096, 0);
    k_enc_conv_t<32><<<dim3(64, 16),  256, 0, stream>>>(A,  encW + 3 * 16384, enc_b + 4 * 64, Bf, 4096,  2048, 0);
    k_enc_conv_t<32><<<dim3(32, 16),  256, 0, stream>>>(Bf, encW + 4 * 16384, enc_b + 5 * 64, z_e, 2048, 1024, 1);
    // vector quantize -> g (padded bf16 [tok][d]) in A
    k_vq<<<256, 512, 0, stream>>>(z_e, cb, idsf, (ushort*)A);

    // decoder L0-L3 (padded bf16 [n][ch] chain): g(A)->Bf->A->Bf->A(d3t)
    k_dec2t<1, true><<<dim3(64, 16),  64, 0, stream>>>((const ushort*)A,  Afrag + 0 * 16384, dec_b + 0 * 64, (ushort*)Bf, 1024);
    k_dec2t<2, true><<<dim3(64, 16),  64, 0, stream>>>((const ushort*)Bf, Afrag + 1 * 16384, dec_b + 1 * 64, (ushort*)A,  2048);
    k_dec2t<4, true><<<dim3(64, 16),  64, 0, stream>>>((const ushort*)A,  Afrag + 2 * 16384, dec_b + 2 * 64, (ushort*)Bf, 4096);
    k_dec2t<4, true><<<dim3(128, 16), 64, 0, stream>>>((const ushort*)Bf, Afrag + 3 * 16384, dec_b + 3 * 64, (ushort*)A,  8192);

    // dec4 + last conv in two 8-batch passes through Bf (d4t bf16, 33.55MB)
    for (int q = 0; q < 2; ++q) {
        k_dec2t<4, false><<<dim3(256, 8), 64, 0, stream>>>(
            (const ushort*)A + (size_t)(q * 8) * 16386 * 64,
            Afrag + 4 * 16384, dec_b + 4 * 64, (ushort*)Bf, 16384);
        k_y<<<dim3(128, 8), 256, 0, stream>>>((const ushort*)Bf, dec_wl, dec_bl, y, q * 8);
    }
}

// Round 20
// 451.148 us; speedup vs baseline: 1.0917x; 1.0917x over previous
//
#include <hip/hip_runtime.h>

#define CH 64

typedef short s16x8 __attribute__((ext_vector_type(8)));
typedef float f32x4 __attribute__((ext_vector_type(4)));

static __device__ __forceinline__ ushort f2bf(float f) {
    union { float f; uint u; } v; v.f = f;
    const uint r = (v.u + 0x7FFFu + ((v.u >> 16) & 1u)) >> 16;
    return (ushort)r;
}
static __device__ __forceinline__ float bf2f(ushort u) {
    union { uint u; float f; } v; v.u = ((uint)u) << 16; return v.f;
}

// =====================================================================
// Prepack encoder weights (5,64,64,4) [o][i][tau] -> [L][i][o][tau]
// =====================================================================
__global__ __launch_bounds__(256) void k_prepack_enc(
    const float* __restrict__ enc_w, float* __restrict__ encW)
{
    const int idx = blockIdx.x * 256 + threadIdx.x;   // 81920
    const int tau = idx & 3;
    const int o = (idx >> 2) & 63;
    const int i = (idx >> 8) & 63;
    const int L = idx >> 14;
    encW[idx] = enc_w[(((size_t)L * 64 + o) * 64 + i) * 4 + tau];
}

// acc = fmaf chain over 4 taps
#define ACC4(A, W, L, H) \
    A = fmaf((W).w, (H).y, fmaf((W).z, (H).x, fmaf((W).y, (L).y, fmaf((W).x, (L).x, (A)))))

// =====================================================================
// ENCODER (fp32): T-pos tile, 256 threads, 16 channels staged/phase.
// =====================================================================
template<int T>
__device__ __forceinline__ void conv_accum_t(
    const float (*inT)[2 * T + 8], const float* __restrict__ wpk, int ibase,
    float acc[4][T / 16], int og, int pg)
{
    const float* wI = wpk + og * 16 + (size_t)ibase * 256;
    for (int ii = 0; ii < 16; ++ii) {
        const float* wp = wI + ii * 256;
        const float4 w0 = *(const float4*)(wp + 0);
        const float4 w1 = *(const float4*)(wp + 4);
        const float4 w2 = *(const float4*)(wp + 8);
        const float4 w3 = *(const float4*)(wp + 12);
        const float* row = inT[ii];
#pragma unroll
        for (int j = 0; j < T / 32; ++j) {
            const int base = 4 * pg + 64 * j;
            const float2 xa = *(const float2*)(row + base);
            const float2 xb = *(const float2*)(row + base + 2);
            const float2 xc = *(const float2*)(row + base + 4);
            ACC4(acc[0][2*j],   w0, xa, xb);
            ACC4(acc[1][2*j],   w1, xa, xb);
            ACC4(acc[2][2*j],   w2, xa, xb);
            ACC4(acc[3][2*j],   w3, xa, xb);
            ACC4(acc[0][2*j+1], w0, xb, xc);
            ACC4(acc[1][2*j+1], w1, xb, xc);
            ACC4(acc[2][2*j+1], w2, xb, xc);
            ACC4(acc[3][2*j+1], w3, xb, xc);
        }
    }
}

template<int T>
__device__ __forceinline__ void conv_epilogue_t(
    float acc[4][T / 16], float* __restrict__ out,
    int b, int m0, int Lout, int transpose, int og, int pg)
{
    if (!transpose) {
#pragma unroll
        for (int oo = 0; oo < 4; ++oo) {
            float* ob = out + ((size_t)b * CH + og * 4 + oo) * Lout + m0 + 2 * pg;
#pragma unroll
            for (int j = 0; j < T / 32; ++j) {
                float2 v;
                v.x = fmaxf(acc[oo][2*j], 0.f);
                v.y = fmaxf(acc[oo][2*j+1], 0.f);
                *(float2*)(ob + 32 * j) = v;
            }
        }
    } else {
#pragma unroll
        for (int j = 0; j < T / 32; ++j)
#pragma unroll
            for (int h = 0; h < 2; ++h) {
                const int ml = 2 * pg + 32 * j + h;
                float* ob = out + ((size_t)b * Lout + m0 + ml) * CH + og * 4;
                float4 v;
                v.x = fmaxf(acc[0][2*j+h], 0.f);
                v.y = fmaxf(acc[1][2*j+h], 0.f);
                v.z = fmaxf(acc[2][2*j+h], 0.f);
                v.w = fmaxf(acc[3][2*j+h], 0.f);
                *(float4*)ob = v;
            }
    }
}

template<int T>
__global__ __launch_bounds__(256) void k_enc_conv_t(
    const float* __restrict__ in, const float* __restrict__ wpk,
    const float* __restrict__ bias, float* __restrict__ out,
    int Lin, int Lout, int transpose)
{
    __shared__ float inT[16][2 * T + 8];
    const int m0 = blockIdx.x * T;
    const int b = blockIdx.y;
    const int tid = threadIdx.x;
    const int og = tid >> 4, pg = tid & 15;
    const float* inb = in + (size_t)b * CH * Lin;
    float acc[4][T / 16];
#pragma unroll
    for (int oo = 0; oo < 4; ++oo) {
        const float bv = bias[og * 4 + oo];
#pragma unroll
        for (int j = 0; j < T / 16; ++j) acc[oo][j] = bv;
    }
    for (int q = 0; q < 4; ++q) {
        {   // stage rows q*16..q*16+15
            const int r = tid >> 4;
            const int i = q * 16 + r;
            const int seg = tid & 15;
            const float* src = inb + (size_t)i * Lin + 2 * m0 + 4 * seg;
            float* dst = inT[r] + 1 + 4 * seg;
#pragma unroll
            for (int t = 0; t < T / 32; ++t) {
                const float4 v = *(const float4*)(src + 64 * t);
                float* d = dst + 64 * t;
                d[0] = v.x;
                *(float2*)(d + 1) = make_float2(v.y, v.z);
                d[3] = v.w;
            }
            if (tid < 32) {                    // edges pl=0 and pl=2T+1
                const int rr = tid & 15, side = tid >> 4;
                const int pl = side ? (2 * T + 1) : 0;
                const int p = 2 * m0 - 1 + pl;
                inT[rr][pl] = (p >= 0 && p < Lin) ? inb[(size_t)(q * 16 + rr) * Lin + p] : 0.f;
            }
        }
        __syncthreads();
        conv_accum_t<T>(inT, wpk, q * 16, acc, og, pg);
        __syncthreads();
    }
    conv_epilogue_t<T>(acc, out, b, m0, Lout, transpose, og, pg);
}

// fused conv0 (1->64) + conv1 (64->64), T=128
__global__ __launch_bounds__(256) void k_enc01(
    const float* __restrict__ x, const float* __restrict__ w0,
    const float* __restrict__ b0, const float* __restrict__ wpk0,
    const float* __restrict__ b1, float* __restrict__ out)
{
    __shared__ float xl[520];
    __shared__ float e0s[16][264];
    const int m0 = blockIdx.x * 128;
    const int b = blockIdx.y;
    const int tid = threadIdx.x;
    const int og = tid >> 4, pg = tid & 15;
    const bool interior = (blockIdx.x != 0) && (blockIdx.x != gridDim.x - 1);
    const float* xb = x + (size_t)b * 65536;
    const int x0i = 4 * m0 - 3;
    if (interior) {
        for (int xi = tid; xi < 518; xi += 256) xl[xi] = xb[x0i + xi];
    } else {
        for (int xi = tid; xi < 518; xi += 256) {
            const int q = x0i + xi;
            xl[xi] = (q >= 0 && q < 65536) ? xb[q] : 0.f;
        }
    }
    float acc[4][8];
#pragma unroll
    for (int oo = 0; oo < 4; ++oo) {
        const float bv = b1[og * 4 + oo];
#pragma unroll
        for (int j = 0; j < 8; ++j) acc[oo][j] = bv;
    }
    const int r = tid >> 4;            // e0 row worker 0..15
    const int oct = tid & 15;          // 16 slots x 17 values
    const int pbase = 2 * m0 - 1;      // e0-pos of pl=0; e0 length = 32768
    __syncthreads();
    for (int q = 0; q < 4; ++q) {
        {
            const int i = q * 16 + r;
            const float4 wv = *(const float4*)(w0 + i * 4);
            const float bv = b0[i];
            if (interior) {
                for (int t = 0; t < 17; ++t) {
                    const int pl = oct * 17 + t;
                    if (pl < 258) {
                        const float* xp = xl + 2 * pl;
                        const float v = fmaf(wv.w, xp[3], fmaf(wv.z, xp[2],
                                        fmaf(wv.y, xp[1], fmaf(wv.x, xp[0], bv))));
                        e0s[r][pl] = fmaxf(v, 0.f);
                    }
                }
            } else {
                for (int t = 0; t < 17; ++t) {
                    const int pl = oct * 17 + t;
                    if (pl < 258) {
                        const int pe = pbase + pl;
                        const float* xp = xl + 2 * pl;
                        const float v = fmaf(wv.w, xp[3], fmaf(wv.z, xp[2],
                                        fmaf(wv.y, xp[1], fmaf(wv.x, xp[0], bv))));
                        e0s[r][pl] = (pe >= 0 && pe < 32768) ? fmaxf(v, 0.f) : 0.f;
                    }
                }
            }
        }
        __syncthreads();
        conv_accum_t<128>(e0s, wpk0, q * 16, acc, og, pg);
        __syncthreads();
    }
    conv_epilogue_t<128>(acc, out, b, m0, 16384, 0, og, pg);
}

// =====================================================================
// VQ — g written as padded bf16 [tok][d]
// =====================================================================
__global__ __launch_bounds__(512) void k_vq(
    const float* __restrict__ z, const float* __restrict__ cb,
    float* __restrict__ idsf, ushort* __restrict__ g)
{
    __shared__ float c2s[1024];
    __shared__ float rval[8][64];
    __shared__ int   ridx[8][64];
    __shared__ int   widx[64];
    const int t0 = blockIdx.x * 64;
    const int tid = threadIdx.x;
    const int lane = tid & 63;
    const int wv = __builtin_amdgcn_readfirstlane(tid >> 6);

    for (int c = tid; c < 1024; c += 512) {
        const float* cp = cb + (size_t)c * 64;
        float s0 = 0.f, s1 = 0.f, s2 = 0.f, s3 = 0.f;
#pragma unroll
        for (int d = 0; d < 64; d += 4) {
            const float4 v = *(const float4*)(cp + d);
            s0 += v.x * v.x; s1 += v.y * v.y; s2 += v.z * v.z; s3 += v.w * v.w;
        }
        c2s[c] = (s0 + s1) + (s2 + s3);
    }
    float pz[64];
    {
        const float* zp = z + (size_t)(t0 + lane) * 64;
#pragma unroll
        for (int d = 0; d < 64; d += 4) {
            const float4 v = *(const float4*)(zp + d);
            pz[d] = -2.f * v.x; pz[d + 1] = -2.f * v.y;
            pz[d + 2] = -2.f * v.z; pz[d + 3] = -2.f * v.w;
        }
    }
    __syncthreads();
    float best = 3.0e38f; int bidx = 0;
    const int cbase = wv * 128;
    for (int cc = 0; cc < 128; ++cc) {
        const int code = cbase + cc;
        const float* cp = cb + (size_t)code * 64;   // uniform -> s_load
        float a0 = 0.f, a1 = 0.f, a2 = 0.f, a3 = 0.f;
#pragma unroll
        for (int d = 0; d < 64; d += 4) {
            a0 += cp[d] * pz[d];
            a1 += cp[d + 1] * pz[d + 1];
            a2 += cp[d + 2] * pz[d + 2];
            a3 += cp[d + 3] * pz[d + 3];
        }
        const float dist = c2s[code] + ((a0 + a1) + (a2 + a3));
        if (dist < best) { best = dist; bidx = code; }
    }
    rval[wv][lane] = best; ridx[wv][lane] = bidx;
    __syncthreads();
    if (tid < 64) {
        float bv = rval[0][tid]; int bi = ridx[0][tid];
#pragma unroll
        for (int k2 = 1; k2 < 8; ++k2) {
            const float v = rval[k2][tid];
            if (v < bv) { bv = v; bi = ridx[k2][tid]; }
        }
        widx[tid] = bi;
        idsf[t0 + tid] = (float)bi;
    }
    __syncthreads();
    const int bb = t0 >> 10;
    const int mb = t0 & 1023;
    ushort* gb = g + ((size_t)bb * 1026 + 1 + mb) * 64;
    for (int e = tid; e < 4096; e += 512) {
        const int d = e & 63;
        const int tok = e >> 6;
        gb[(size_t)tok * 64 + d] = f2bf(cb[(size_t)widx[tok] * 64 + d]);
    }
    if (mb == 0 && tid < 16) {
        ushort4 zz = {0, 0, 0, 0};
        *(ushort4*)(g + ((size_t)bb * 1026) * 64 + tid * 4) = zz;
    }
    if (mb == 960 && tid < 16) {
        ushort4 zz = {0, 0, 0, 0};
        *(ushort4*)(g + ((size_t)bb * 1026 + 1025) * 64 + tid * 4) = zz;
    }
}

// =====================================================================
// DECODER: padded bf16 [n][ch] inter-layer format. k_dec2t<NCG,PAD>
// 1-wave blocks; NCG u-col groups share the wave's A-fragment loads.
// =====================================================================
__global__ __launch_bounds__(256) void k_prepack(
    const float* __restrict__ dec_w, ushort* __restrict__ Afrag)
{
    const int idx = blockIdx.x * 256 + threadIdx.x;   // 81920
    const int j    = idx & 7;
    const int lane = (idx >> 3) & 63;
    const int kt   = (idx >> 9) & 1;
    const int m    = (idx >> 10) & 3;
    const int tap  = (idx >> 12) & 3;
    const int L    = idx >> 14;
    const int o = m * 16 + (lane & 15);
    const int i = kt * 32 + ((lane >> 4) << 3) + j;
    Afrag[idx] = f2bf(dec_w[(((size_t)L * 64 + i) * 64 + o) * 4 + tap]);
}

template<int NCG, bool PAD>
__global__ __launch_bounds__(64) void k_dec2t(
    const ushort* __restrict__ Xt, const ushort* __restrict__ AfragL,
    const float* __restrict__ bias, ushort* __restrict__ Yt, int Lin)
{
    const int u0 = blockIdx.x * (16 * NCG);
    const int b  = blockIdx.y;
    const int tid = threadIdx.x;
    const int Lout = Lin * 2;
    const ushort* Xb = Xt + ((size_t)b * (Lin + 2) + 1) * 64;
    ushort* Yb = PAD ? Yt + ((size_t)b * (Lout + 2) + 1) * 64
                     : Yt + (size_t)b * Lout * 64;

    const int lane = tid & 63;
    const int col = lane & 15, kg = lane >> 4;
    s16x8 Bm1[NCG][2], B0[NCG][2], Bp1[NCG][2];
#pragma unroll
    for (int g = 0; g < NCG; ++g) {
        const ushort* basep = Xb + (size_t)(u0 + col + 16 * g) * 64 + kg * 8;
#pragma unroll
        for (int kt = 0; kt < 2; ++kt) {
            Bm1[g][kt] = *(const s16x8*)(basep - 64 + kt * 32);
            B0[g][kt]  = *(const s16x8*)(basep + kt * 32);
            Bp1[g][kt] = *(const s16x8*)(basep + 64 + kt * 32);
        }
    }
    const s16x8* Af = (const s16x8*)AfragL;
#pragma unroll
    for (int m = 0; m < 4; ++m) {
        s16x8 a1[2], a3[2], a2[2], a0[2];
#pragma unroll
        for (int kt = 0; kt < 2; ++kt) {
            a1[kt] = Af[((1 * 4 + m) * 2 + kt) * 64 + lane];
            a3[kt] = Af[((3 * 4 + m) * 2 + kt) * 64 + lane];
            a2[kt] = Af[((2 * 4 + m) * 2 + kt) * 64 + lane];
            a0[kt] = Af[((0 * 4 + m) * 2 + kt) * 64 + lane];
        }
        const float4 bm4 = *(const float4*)(bias + m * 16 + kg * 4);
        const float bb[4] = {bm4.x, bm4.y, bm4.z, bm4.w};
#pragma unroll
        for (int g = 0; g < NCG; ++g) {
            f32x4 aE = {0.f, 0.f, 0.f, 0.f};
            f32x4 aO = {0.f, 0.f, 0.f, 0.f};
#pragma unroll
            for (int kt = 0; kt < 2; ++kt) {
                aE = __builtin_amdgcn_mfma_f32_16x16x32_bf16(a1[kt], B0[g][kt],  aE, 0, 0, 0);
                aE = __builtin_amdgcn_mfma_f32_16x16x32_bf16(a3[kt], Bm1[g][kt], aE, 0, 0, 0);
                aO = __builtin_amdgcn_mfma_f32_16x16x32_bf16(a2[kt], B0[g][kt],  aO, 0, 0, 0);
                aO = __builtin_amdgcn_mfma_f32_16x16x32_bf16(a0[kt], Bp1[g][kt], aO, 0, 0, 0);
            }
            const size_t n2 = 2 * (size_t)(u0 + col + 16 * g);
            ushort4 pe, po;
            pe.x = f2bf(fmaxf(aE[0] + bb[0], 0.f));
            pe.y = f2bf(fmaxf(aE[1] + bb[1], 0.f));
            pe.z = f2bf(fmaxf(aE[2] + bb[2], 0.f));
            pe.w = f2bf(fmaxf(aE[3] + bb[3], 0.f));
            po.x = f2bf(fmaxf(aO[0] + bb[0], 0.f));
            po.y = f2bf(fmaxf(aO[1] + bb[1], 0.f));
            po.z = f2bf(fmaxf(aO[2] + bb[2], 0.f));
            po.w = f2bf(fmaxf(aO[3] + bb[3], 0.f));
            *(ushort4*)(Yb + n2 * 64 + m * 16 + kg * 4) = pe;
            *(ushort4*)(Yb + (n2 + 1) * 64 + m * 16 + kg * 4) = po;
        }
    }
    if (PAD) {
        if (blockIdx.x == 0 && tid < 16) {
            ushort4 zz = {0, 0, 0, 0};
            *(ushort4*)(Yt + ((size_t)b * (Lout + 2)) * 64 + tid * 4) = zz;
        }
        if (u0 + 16 * NCG >= Lin && tid < 16) {
            ushort4 zz = {0, 0, 0, 0};
            *(ushort4*)(Yb + (size_t)Lout * 64 + tid * 4) = zz;
        }
    }
}

// last convT (64->1, no relu): y[2v] / y[2v+1] from d4t rows v-1, v, v+1.
__global__ __launch_bounds__(256) void k_y(
    const ushort* __restrict__ d4t, const float* __restrict__ wl,
    const float* __restrict__ blp, float* __restrict__ y, int bbase)
{
    const int v = blockIdx.x * 256 + threadIdx.x;
    const int b = blockIdx.y;
    const ushort* r0 = d4t + ((size_t)b * 32768 + v) * 64;
    const bool hm = v > 0, hp = v < 32767;
    const ushort* rm = hm ? r0 - 64 : r0;
    const ushort* rp = hp ? r0 + 64 : r0;
    const s16x8 zv = {0, 0, 0, 0, 0, 0, 0, 0};
    float y0a = 0.f, y0b = 0.f, y1a = 0.f, y1b = 0.f;
#pragma unroll
    for (int c = 0; c < 8; ++c) {
        const s16x8 a0 = *(const s16x8*)(r0 + 8 * c);
        s16x8 am = *(const s16x8*)(rm + 8 * c);
        s16x8 ap = *(const s16x8*)(rp + 8 * c);
        if (!hm) am = zv;
        if (!hp) ap = zv;
#pragma unroll
        for (int e = 0; e < 8; e += 2) {
            const float4 wA = *(const float4*)(wl + (8 * c + e) * 4);
            const float4 wB = *(const float4*)(wl + (8 * c + e + 1) * 4);
            y0a = fmaf(wA.y, bf2f((ushort)a0[e]),     fmaf(wA.w, bf2f((ushort)am[e]),     y0a));
            y1a = fmaf(wA.z, bf2f((ushort)a0[e]),     fmaf(wA.x, bf2f((ushort)ap[e]),     y1a));
            y0b = fmaf(wB.y, bf2f((ushort)a0[e + 1]), fmaf(wB.w, bf2f((ushort)am[e + 1]), y0b));
            y1b = fmaf(wB.z, bf2f((ushort)a0[e + 1]), fmaf(wB.x, bf2f((ushort)ap[e + 1]), y1b));
        }
    }
    float2 out;
    out.x = blp[0] + (y0a + y0b);
    out.y = blp[0] + (y1a + y1b);
    *(float2*)(y + (size_t)(bbase + b) * 65536 + 2 * v) = out;
}

extern "C" void kernel_launch(void* const* d_in, const int* in_sizes, int n_in,
                              void* d_out, int out_size, void* d_ws, size_t ws_size,
                              hipStream_t stream) {
    const float* x      = (const float*)d_in[0];
    const float* enc_w0 = (const float*)d_in[1];
    const float* enc_w  = (const float*)d_in[2];   // (5,64,64,4)
    const float* enc_b  = (const float*)d_in[3];   // (6,64)
    const float* cb     = (const float*)d_in[4];   // (1024,64)
    const float* dec_w  = (const float*)d_in[5];   // (5,64,64,4) [in][out][k]
    const float* dec_wl = (const float*)d_in[6];   // (64,1,4)
    const float* dec_b  = (const float*)d_in[7];   // (5,64)
    const float* dec_bl = (const float*)d_in[8];   // (1,)
    float* y    = (float*)d_out;                   // (16,1,65536)
    float* z_e  = y + 1048576;                     // (16384,64)
    float* idsf = y + 2097152;                     // (16384,)

    // workspace overlay: A = 16.7M floats (67MB), Bf = 8.4M floats (33.6MB)
    float* A  = (float*)d_ws;
    float* Bf = A + 16777216;

    float*  encW  = y + 14 * 65536;
    ushort* Afrag = (ushort*)(encW + 81920);

    k_prepack_enc<<<dim3(320), 256, 0, stream>>>(enc_w, encW);
    k_prepack<<<dim3(320), 256, 0, stream>>>(dec_w, Afrag);

    // encoder (fp32)
    k_enc01<<<dim3(128, 16), 256, 0, stream>>>(x, enc_w0, enc_b, encW, enc_b + 64, A);
    k_enc_conv_t<128><<<dim3(64, 16), 256, 0, stream>>>(A,  encW + 1 * 16384, enc_b + 2 * 64, Bf, 16384, 8192, 0);
    k_enc_conv_t<64><<<dim3(64, 16),  256, 0, stream>>>(Bf, encW + 2 * 16384, enc_b + 3 * 64, A,  8192,  4096, 0);
    k_enc_conv_t<32><<<dim3(64, 16),  256, 0, stream>>>(A,  encW + 3 * 16384, enc_b + 4 * 64, Bf, 4096,  2048, 0);
    k_enc_conv_t<32><<<dim3(32, 16),  256, 0, stream>>>(Bf, encW + 4 * 16384, enc_b + 5 * 64, z_e, 2048, 1024, 1);
    // vector quantize -> g (padded bf16 [tok][d]) in A
    k_vq<<<256, 512, 0, stream>>>(z_e, cb, idsf, (ushort*)A);

    // decoder L0-L3 (padded bf16 [n][ch] chain): g(A)->Bf->A->Bf->A(d3t)
    k_dec2t<1, true><<<dim3(64, 16),  64, 0, stream>>>((const ushort*)A,  Afrag + 0 * 16384, dec_b + 0 * 64, (ushort*)Bf, 1024);
    k_dec2t<2, true><<<dim3(64, 16),  64, 0, stream>>>((const ushort*)Bf, Afrag + 1 * 16384, dec_b + 1 * 64, (ushort*)A,  2048);
    k_dec2t<4, true><<<dim3(64, 16),  64, 0, stream>>>((const ushort*)A,  Afrag + 2 * 16384, dec_b + 2 * 64, (ushort*)Bf, 4096);
    k_dec2t<4, true><<<dim3(128, 16), 64, 0, stream>>>((const ushort*)Bf, Afrag + 3 * 16384, dec_b + 3 * 64, (ushort*)A,  8192);

    // dec4 + last conv in two 8-batch passes through Bf (d4t bf16, 33.55MB)
    for (int q = 0; q < 2; ++q) {
        k_dec2t<4, false><<<dim3(256, 8), 64, 0, stream>>>(
            (const ushort*)A + (size_t)(q * 8) * 16386 * 64,
            Afrag + 4 * 16384, dec_b + 4 * 64, (ushort*)Bf, 16384);
        k_y<<<dim3(128, 8), 256, 0, stream>>>((const ushort*)Bf, dec_wl, dec_bl, y, q * 8);
    }
}